// Round 11
// baseline (197.394 us; speedup 1.0000x reference)
//
#include <hip/hip_runtime.h>
#include <math.h>

#define NPTS 16384
#define KN 32
#define C 256
#define NQ 8192              // 8 * 1024 queries
#define PF_ELEMS (NQ * C)

#define W1P_ELEMS (3 * 16 * 64 * 8)                 // 24576  (Ktiles=3, Ntiles=16)
#define W2P_ELEMS (8 * 16 * 64 * 8)                 // 65536  (Ktiles=8)
#define HSTR 264                                    // halves per H16 row

typedef _Float16 half8 __attribute__((ext_vector_type(8)));
typedef _Float16 half4v __attribute__((ext_vector_type(4)));
typedef _Float16 half2t __attribute__((ext_vector_type(2)));
typedef float f32x4 __attribute__((ext_vector_type(4)));

// tanh-approx GeLU: max err ~3e-4.  y = x - x/(e^{2u}+1)
__device__ __forceinline__ float gelu_tanh(float x) {
    const float t  = x * x;
    const float p2 = fmaf(t, 0.0713548162726f, 1.59576912161f);
    const float e  = __expf(x * p2);
    return x - x * __builtin_amdgcn_rcpf(e + 1.0f);
}

// ---------------------------------------------------------------------------
// Pack W1 (91x256 + b1 folded at k=91, K-padded to 96) and W2 (256x256) into
// f16 fragment order (verified round 2; A/B per-lane layouts are identical
// for 16x16x32):  flat = ((kt*16 + nt)*64 + lane)*8 + j
//   k = kt*32 + (lane>>4)*8 + j ;  ch = nt*16 + (lane&15)
// ---------------------------------------------------------------------------
__global__ void prep_w_kernel(const float* __restrict__ W1,
                              const float* __restrict__ b1,
                              const float* __restrict__ W2,
                              _Float16* __restrict__ wp) {
    const int idx = blockIdx.x * 256 + threadIdx.x;   // 0 .. 90111
    if (idx < 96 * 256) {
        const int k = idx >> 8, n = idx & 255;
        const float v = (k < 91) ? W1[k * 256 + n] : ((k == 91) ? b1[n] : 0.0f);
        const int kt = k >> 5, quad = (k >> 3) & 3, j = k & 7;
        const int nt = n >> 4, l15 = n & 15;
        wp[(((kt * 16 + nt) * 64) + quad * 16 + l15) * 8 + j] = (_Float16)v;
    } else {
        const int e = idx - 96 * 256;
        const int k = e >> 8, n = e & 255;
        const int kt = k >> 5, quad = (k >> 3) & 3, j = k & 7;
        const int nt = n >> 4, l15 = n & 15;
        wp[W1P_ELEMS + (((kt * 16 + nt) * 64) + quad * 16 + l15) * 8 + j] =
            (_Float16)W2[k * 256 + n];
    }
}

// ---------------------------------------------------------------------------
// Fused: ball-query + gather/posenc + MLP1(LN,GeLU) + MLP2(LN) + max.
// Round-11: round-10 structure + Xs/H16 LDS OVERLAY. Xs dies at GEMM1's
// last fragment read; H16 is first written after the LN1 sums barrier,
// which already orders the transition — overlay costs zero extra barriers.
// LDS 25.1 -> 18.4 KB; __launch_bounds__(256,7) -> 7 blocks/CU.
// Register budget at 7 waves/EU = 73 (using 40 VGPR + 32 acc AGPR = 72).
// No runtime-indexed private arrays (round-3 lesson).
// ---------------------------------------------------------------------------
__global__ void __launch_bounds__(256, 7)
encoder_fused(const float* __restrict__ xyz,
              const float* __restrict__ pf,
              const float* __restrict__ ctr,
              const float* __restrict__ g1, const float* __restrict__ be1,
              const float* __restrict__ b2, const float* __restrict__ g2,
              const float* __restrict__ be2,
              const _Float16* __restrict__ w1p,
              const _Float16* __restrict__ w2p,
              float* __restrict__ out0,      // patch_feature [8192][256]
              float* __restrict__ out1) {    // neighbor idx as float [8192][32]
    const int q = blockIdx.x;
    const int b = q >> 10;
    const int t = threadIdx.x;
    const int w = t >> 6;
    const int lane = t & 63;
    const int quad = lane >> 4;
    const int l15  = lane & 15;

    // Overlaid region: Xs f16[32][104] (phase1 -> GEMM1) then H16 f16[32][264]
    // (LN1 store -> phase 6). Transition ordered by the LN1 sums barrier.
    __shared__ __align__(16) unsigned char H16raw[KN * HSTR * 2];  // 16896
    __shared__ float sums[KN][10];                                  // 1280
    __shared__ int nbr[KN];
    __shared__ int wcnt[2][4];

    _Float16 (*H16)[HSTR] = (_Float16(*)[HSTR])H16raw;
    _Float16 (*Xs)[104]   = (_Float16(*)[104])H16raw;   // OVERLAY

    // ---- Phase 0: ball query (block-wide ordered compaction) ----
    // first-32-ascending == reference sort+slice; exact unfused fp32 formula.
    const float* xb = xyz + (size_t)b * NPTS * 3;
    const float cx = ctr[q * 3 + 0];
    const float cy = ctr[q * 3 + 1];
    const float cz = ctr[q * 3 + 2];
    const float sc = __fadd_rn(__fadd_rn(__fmul_rn(cx, cx), __fmul_rn(cy, cy)),
                               __fmul_rn(cz, cz));

    int found = 0;
    int par = 0;
    for (int base = 0; base < NPTS; base += 256) {
        const int n = base + t;
        const float px = xb[n * 3 + 0];
        const float py = xb[n * 3 + 1];
        const float pz = xb[n * 3 + 2];
        const float sp = __fadd_rn(__fadd_rn(__fmul_rn(px, px), __fmul_rn(py, py)),
                                   __fmul_rn(pz, pz));
        const float dt = __fadd_rn(__fadd_rn(__fmul_rn(cx, px), __fmul_rn(cy, py)),
                                   __fmul_rn(cz, pz));
        const float sqr = __fsub_rn(__fadd_rn(sc, sp), __fmul_rn(2.0f, dt));
        const bool inball = (sqr <= 0.0625f);

        const unsigned long long m = __ballot(inball);
        if (lane == 0) wcnt[par][w] = (int)__popcll(m);
        __syncthreads();
        int pre = found;
        if (w > 0) pre += wcnt[par][0];
        if (w > 1) pre += wcnt[par][1];
        if (w > 2) pre += wcnt[par][2];
        const int tot = found + wcnt[par][0] + wcnt[par][1] + wcnt[par][2] + wcnt[par][3];
        const int pos = pre + (int)__popcll(m & ((1ull << lane) - 1ull));
        if (inball && pos < KN) nbr[pos] = n;
        found = tot;                  // block-uniform
        par ^= 1;
        if (found >= KN) break;
    }
    __syncthreads();                  // nbr visible to all
    const int count = (found < KN) ? found : KN;
    const int first = (count > 0) ? nbr[0] : NPTS;

    if (t < KN)
        out1[(size_t)q * KN + t] = (float)((t < count) ? nbr[t] : first);

    // ---- Phase 1: gather + rel + posenc into Xs (f16; k=91 is 1.0 for b1) ----
    {
        const int k  = t >> 3;
        const int tc = t & 7;
        const int nidx = (k < count) ? nbr[k] : first;
        const int n = (nidx < NPTS) ? nidx : NPTS - 1;   // JAX OOB gather clamp
        const float rx = xb[n * 3 + 0] - cx;
        const float ry = xb[n * 3 + 1] - cy;
        const float rz = xb[n * 3 + 2] - cz;
        const float* pfr = pf + ((size_t)b * NPTS + n) * 64;

        const float4 f0 = *(const float4*)(pfr + tc * 8);
        const float4 f1 = *(const float4*)(pfr + tc * 8 + 4);
        half8 hv;
        hv[0] = (_Float16)f0.x; hv[1] = (_Float16)f0.y;
        hv[2] = (_Float16)f0.z; hv[3] = (_Float16)f0.w;
        hv[4] = (_Float16)f1.x; hv[5] = (_Float16)f1.y;
        hv[6] = (_Float16)f1.z; hv[7] = (_Float16)f1.w;
        *(half8*)&Xs[k][tc * 8] = hv;

        half4v ov;
        #pragma unroll
        for (int j = 0; j < 4; ++j) {
            const int c = 64 + tc * 4 + j;
            float v;
            if (c < 67) {
                v = (c == 64) ? rx : ((c == 65) ? ry : rz);
            } else if (c < 91) {
                const int jj = c - 67;
                const int d = jj >> 3;
                const int mm = jj & 7;
                const float f = (float)(1 << (mm & 3));
                const float r = (d == 0) ? rx : ((d == 1) ? ry : rz);
                v = (mm < 4) ? __sinf(r * f) : __cosf(r * f);
            } else if (c == 91) {
                v = 1.0f;               // bias row (b1 folded into W1 pack)
            } else {
                v = 0.0f;
            }
            ov[j] = (_Float16)v;
        }
        *(half4v*)&Xs[k][64 + tc * 4] = ov;
    }
    __syncthreads();

    f32x4 acc[2][4];   // [point-tile mt][channel-tile nt]; lane: ch=(w*4+nt)*16+quad*4+r, pt=mt*16+l15

    // ---- GEMM1: W1^T as A, X as B  ->  acc (+b1 via folded row) ----
    #pragma unroll
    for (int mt = 0; mt < 2; ++mt)
        #pragma unroll
        for (int nt = 0; nt < 4; ++nt)
            acc[mt][nt] = (f32x4){0.f, 0.f, 0.f, 0.f};

    #pragma unroll
    for (int kt = 0; kt < 3; ++kt) {
        const half8 x0 = *(const half8*)&Xs[l15][kt * 32 + quad * 8];
        const half8 x1 = *(const half8*)&Xs[16 + l15][kt * 32 + quad * 8];
        #pragma unroll
        for (int nt = 0; nt < 4; ++nt) {
            const half8 wf = *(const half8*)&w1p[((kt * 16 + w * 4 + nt) * 64 + lane) * 8];
            acc[0][nt] = __builtin_amdgcn_mfma_f32_16x16x32_f16(wf, x0, acc[0][nt], 0, 0, 0);
            acc[1][nt] = __builtin_amdgcn_mfma_f32_16x16x32_f16(wf, x1, acc[1][nt], 0, 0, 0);
        }
    }

    // ---- LN1 + GeLU, register-resident; store f16 rows for GEMM2 ----
    // NOTE: the sums __syncthreads below is also the Xs->H16 overlay fence
    // (all GEMM1 Xs reads precede it; all H16 writes follow it).
    {
        float s0 = 0.f, z0 = 0.f, s1 = 0.f, z1 = 0.f;
        #pragma unroll
        for (int nt = 0; nt < 4; ++nt)
            #pragma unroll
            for (int r = 0; r < 4; ++r) {
                const float a0 = acc[0][nt][r], a1 = acc[1][nt][r];
                s0 += a0; z0 = fmaf(a0, a0, z0);
                s1 += a1; z1 = fmaf(a1, a1, z1);
            }
        s0 += __shfl_xor(s0, 16, 64); s0 += __shfl_xor(s0, 32, 64);
        z0 += __shfl_xor(z0, 16, 64); z0 += __shfl_xor(z0, 32, 64);
        s1 += __shfl_xor(s1, 16, 64); s1 += __shfl_xor(s1, 32, 64);
        z1 += __shfl_xor(z1, 16, 64); z1 += __shfl_xor(z1, 32, 64);
        if (quad == 0) {
            float2 v0; v0.x = s0; v0.y = z0;
            float2 v1; v1.x = s1; v1.y = z1;
            *(float2*)&sums[l15][2 * w]      = v0;
            *(float2*)&sums[16 + l15][2 * w] = v1;
        }
        __syncthreads();
        float st0 = 0.f, zt0 = 0.f, st1 = 0.f, zt1 = 0.f;
        #pragma unroll
        for (int ww = 0; ww < 4; ++ww) {
            const float2 v0 = *(const float2*)&sums[l15][2 * ww];
            const float2 v1 = *(const float2*)&sums[16 + l15][2 * ww];
            st0 += v0.x; zt0 += v0.y;
            st1 += v1.x; zt1 += v1.y;
        }
        const float mu0 = st0 * (1.0f / 256.0f);
        const float mu1 = st1 * (1.0f / 256.0f);
        const float rs0 = __builtin_amdgcn_rsqf(fmaf(zt0, 1.0f / 256.0f, -mu0 * mu0) + 1e-5f);
        const float rs1 = __builtin_amdgcn_rsqf(fmaf(zt1, 1.0f / 256.0f, -mu1 * mu1) + 1e-5f);

        #pragma unroll
        for (int nt = 0; nt < 4; ++nt) {
            const int chb = (w * 4 + nt) * 16 + quad * 4;
            const f32x4 g  = *(const f32x4*)&g1[chb];
            const f32x4 be = *(const f32x4*)&be1[chb];
            half4v h0, h1;
            #pragma unroll
            for (int r = 0; r < 4; ++r) {
                const float y0 = fmaf((acc[0][nt][r] - mu0) * rs0, g[r], be[r]);
                const float y1 = fmaf((acc[1][nt][r] - mu1) * rs1, g[r], be[r]);
                h0[r] = (_Float16)gelu_tanh(y0);
                h1[r] = (_Float16)gelu_tanh(y1);
            }
            *(half4v*)&H16[l15][chb]      = h0;
            *(half4v*)&H16[16 + l15][chb] = h1;
        }
    }
    __syncthreads();

    // ---- GEMM2: W2^T as A, H as B ----
    #pragma unroll
    for (int mt = 0; mt < 2; ++mt)
        #pragma unroll
        for (int nt = 0; nt < 4; ++nt)
            acc[mt][nt] = (f32x4){0.f, 0.f, 0.f, 0.f};

    #pragma unroll
    for (int kt = 0; kt < 8; ++kt) {
        const half8 h0 = *(const half8*)&H16[l15][kt * 32 + quad * 8];
        const half8 h1 = *(const half8*)&H16[16 + l15][kt * 32 + quad * 8];
        #pragma unroll
        for (int nt = 0; nt < 4; ++nt) {
            const half8 wf = *(const half8*)&w2p[((kt * 16 + w * 4 + nt) * 64 + lane) * 8];
            acc[0][nt] = __builtin_amdgcn_mfma_f32_16x16x32_f16(wf, h0, acc[0][nt], 0, 0, 0);
            acc[1][nt] = __builtin_amdgcn_mfma_f32_16x16x32_f16(wf, h1, acc[1][nt], 0, 0, 0);
        }
    }
    __syncthreads();   // ALL B-reads of H16 done before in-place LN2 store

    // ---- +b2, LN2 stats (register) + normalize -> f16 back into H16 ----
    {
        #pragma unroll
        for (int nt = 0; nt < 4; ++nt) {
            const int chb = (w * 4 + nt) * 16 + quad * 4;
            const f32x4 bv = *(const f32x4*)&b2[chb];
            #pragma unroll
            for (int r = 0; r < 4; ++r) {
                acc[0][nt][r] += bv[r];
                acc[1][nt][r] += bv[r];
            }
        }
        float s0 = 0.f, z0 = 0.f, s1 = 0.f, z1 = 0.f;
        #pragma unroll
        for (int nt = 0; nt < 4; ++nt)
            #pragma unroll
            for (int r = 0; r < 4; ++r) {
                const float a0 = acc[0][nt][r], a1 = acc[1][nt][r];
                s0 += a0; z0 = fmaf(a0, a0, z0);
                s1 += a1; z1 = fmaf(a1, a1, z1);
            }
        s0 += __shfl_xor(s0, 16, 64); s0 += __shfl_xor(s0, 32, 64);
        z0 += __shfl_xor(z0, 16, 64); z0 += __shfl_xor(z0, 32, 64);
        s1 += __shfl_xor(s1, 16, 64); s1 += __shfl_xor(s1, 32, 64);
        z1 += __shfl_xor(z1, 16, 64); z1 += __shfl_xor(z1, 32, 64);
        if (quad == 0) {
            float2 v0; v0.x = s0; v0.y = z0;
            float2 v1; v1.x = s1; v1.y = z1;
            *(float2*)&sums[l15][2 * w]      = v0;
            *(float2*)&sums[16 + l15][2 * w] = v1;
        }
        __syncthreads();
        float st0 = 0.f, zt0 = 0.f, st1 = 0.f, zt1 = 0.f;
        #pragma unroll
        for (int ww = 0; ww < 4; ++ww) {
            const float2 v0 = *(const float2*)&sums[l15][2 * ww];
            const float2 v1 = *(const float2*)&sums[16 + l15][2 * ww];
            st0 += v0.x; zt0 += v0.y;
            st1 += v1.x; zt1 += v1.y;
        }
        const float mu0 = st0 * (1.0f / 256.0f);
        const float mu1 = st1 * (1.0f / 256.0f);
        const float rs0 = __builtin_amdgcn_rsqf(fmaf(zt0, 1.0f / 256.0f, -mu0 * mu0) + 1e-5f);
        const float rs1 = __builtin_amdgcn_rsqf(fmaf(zt1, 1.0f / 256.0f, -mu1 * mu1) + 1e-5f);

        #pragma unroll
        for (int nt = 0; nt < 4; ++nt) {
            const int chb = (w * 4 + nt) * 16 + quad * 4;
            const f32x4 g  = *(const f32x4*)&g2[chb];
            const f32x4 be = *(const f32x4*)&be2[chb];
            half4v h0, h1;
            #pragma unroll
            for (int r = 0; r < 4; ++r) {
                h0[r] = (_Float16)fmaf((acc[0][nt][r] - mu0) * rs0, g[r], be[r]);
                h1[r] = (_Float16)fmaf((acc[1][nt][r] - mu1) * rs1, g[r], be[r]);
            }
            *(half4v*)&H16[l15][chb]      = h0;
            *(half4v*)&H16[16 + l15][chb] = h1;
        }
    }
    __syncthreads();

    // ---- Phase 6: packed max over 32 points, coalesced float2 store ----
    if (t < 128) {
        const _Float16* Hf = &H16[0][0];
        half2t mx = *(const half2t*)(Hf + 2 * t);
        #pragma unroll
        for (int r = 1; r < KN; ++r) {
            const half2t v = *(const half2t*)(Hf + r * HSTR + 2 * t);
            mx = __builtin_elementwise_max(mx, v);
        }
        float2 o2;
        o2.x = (float)mx[0];
        o2.y = (float)mx[1];
        *(float2*)&out0[(size_t)q * C + 2 * t] = o2;
    }
}

extern "C" void kernel_launch(void* const* d_in, const int* in_sizes, int n_in,
                              void* d_out, int out_size, void* d_ws, size_t ws_size,
                              hipStream_t stream) {
    const float* xyz = (const float*)d_in[0];
    const float* pf  = (const float*)d_in[1];
    const float* ctr = (const float*)d_in[2];
    const float* W1  = (const float*)d_in[3];
    const float* b1  = (const float*)d_in[4];
    const float* g1  = (const float*)d_in[5];
    const float* be1 = (const float*)d_in[6];
    const float* W2  = (const float*)d_in[7];
    const float* b2  = (const float*)d_in[8];
    const float* g2  = (const float*)d_in[9];
    const float* be2 = (const float*)d_in[10];

    float* out = (float*)d_out;
    _Float16* wp = (_Float16*)d_ws;

    prep_w_kernel<<<(96 * 256 + 65536) / 256, 256, 0, stream>>>(W1, b1, W2, wp);
    encoder_fused<<<NQ, 256, 0, stream>>>(xyz, pf, ctr,
                                          g1, be1, b2, g2, be2,
                                          wp, wp + W1P_ELEMS,
                                          out, out + PF_ELEMS);
}

// Round 12
// 192.744 us; speedup vs baseline: 1.0241x; 1.0241x over previous
//
#include <hip/hip_runtime.h>
#include <math.h>

#define NPTS 16384
#define KN 32
#define C 256
#define NQ 8192              // 8 * 1024 queries
#define PF_ELEMS (NQ * C)

#define W1P_ELEMS (3 * 16 * 64 * 8)                 // 24576  (Ktiles=3, Ntiles=16)
#define W2P_ELEMS (8 * 16 * 64 * 8)                 // 65536  (Ktiles=8)
#define HSTR 264                                    // halves per H16 row

typedef _Float16 half8 __attribute__((ext_vector_type(8)));
typedef _Float16 half4v __attribute__((ext_vector_type(4)));
typedef _Float16 half2t __attribute__((ext_vector_type(2)));
typedef float f32x4 __attribute__((ext_vector_type(4)));

union H8u { half8 v; half2t h2[4]; };

__device__ __forceinline__ float fdot2f(half2t a, half2t b, float c) {
#if __has_builtin(__builtin_amdgcn_fdot2)
    return __builtin_amdgcn_fdot2(a, b, c, false);
#else
    return fmaf((float)a[1], (float)b[1], fmaf((float)a[0], (float)b[0], c));
#endif
}

// tanh-approx GeLU: max err ~3e-4.  y = x - x/(e^{2u}+1)
__device__ __forceinline__ float gelu_tanh(float x) {
    const float t  = x * x;
    const float p2 = fmaf(t, 0.0713548162726f, 1.59576912161f);
    const float e  = __expf(x * p2);
    return x - x * __builtin_amdgcn_rcpf(e + 1.0f);
}

__device__ __forceinline__ void stat8(const H8u& u, half2t ones, float& s, float& s2) {
    #pragma unroll
    for (int j = 0; j < 4; ++j) {
        s  = fdot2f(u.h2[j], ones, s);
        s2 = fdot2f(u.h2[j], u.h2[j], s2);
    }
}

__device__ __forceinline__ void norm_gelu8(H8u& u, const H8u& g, const H8u& be,
                                           half2t rsh, half2t nmuh) {
    #pragma unroll
    for (int j = 0; j < 4; ++j) {
        const half2t A = g.h2[j] * rsh;
        const half2t B = A * nmuh + be.h2[j];
        const half2t y = u.h2[j] * A + B;
        half2t o;
        o[0] = (_Float16)gelu_tanh((float)y[0]);
        o[1] = (_Float16)gelu_tanh((float)y[1]);
        u.h2[j] = o;
    }
}

__device__ __forceinline__ void norm8(H8u& u, const H8u& g, const H8u& be,
                                      half2t rsh, half2t nmuh) {
    #pragma unroll
    for (int j = 0; j < 4; ++j) {
        const half2t A = g.h2[j] * rsh;
        const half2t B = A * nmuh + be.h2[j];
        u.h2[j] = u.h2[j] * A + B;
    }
}

// ---------------------------------------------------------------------------
// Pack W1 (91x256 + b1 folded at k=91, K-padded to 96) and W2 (256x256) into
// f16 fragment order (layout verified round 2):
//   flat = ((kt*16 + nt)*64 + lane)*8 + j
//   k = kt*32 + (lane>>4)*8 + j ;  ch = nt*16 + (lane&15)
// ---------------------------------------------------------------------------
__global__ void prep_w_kernel(const float* __restrict__ W1,
                              const float* __restrict__ b1,
                              const float* __restrict__ W2,
                              _Float16* __restrict__ wp) {
    const int idx = blockIdx.x * 256 + threadIdx.x;   // 0 .. 90111
    if (idx < 96 * 256) {
        const int k = idx >> 8, n = idx & 255;
        const float v = (k < 91) ? W1[k * 256 + n] : ((k == 91) ? b1[n] : 0.0f);
        const int kt = k >> 5, quad = (k >> 3) & 3, j = k & 7;
        const int nt = n >> 4, l15 = n & 15;
        wp[(((kt * 16 + nt) * 64) + quad * 16 + l15) * 8 + j] = (_Float16)v;
    } else {
        const int e = idx - 96 * 256;
        const int k = e >> 8, n = e & 255;
        const int kt = k >> 5, quad = (k >> 3) & 3, j = k & 7;
        const int nt = n >> 4, l15 = n & 15;
        wp[W1P_ELEMS + (((kt * 16 + nt) * 64) + quad * 16 + l15) * 8 + j] =
            (_Float16)W2[k * 256 + n];
    }
}

// ---------------------------------------------------------------------------
// Fused: ball-query + gather/posenc + MLP1(LN,GeLU) + MLP2(LN) + max.
// Round-12 hybrid: operand-swapped MFMA (channels-in-lane C layout -> 8
// contiguous ds_write_b64 C-stores, b1 folded) + round-8's LDS-based LN
// epilogues (acc dies at the C-store -> no register spill; rounds 10/11's
// register epilogue spilled: WRITE_SIZE 26/52 MB). Xs/H16 overlay with an
// explicit fence barrier after GEMM1. No XOR swizzle (no column stores).
// __launch_bounds__(256,7): round-8 pressure (~72 regs) fits the 73 budget.
// No runtime-indexed private arrays (round-3 lesson).
// ---------------------------------------------------------------------------
__global__ void __launch_bounds__(256, 7)
encoder_fused(const float* __restrict__ xyz,
              const float* __restrict__ pf,
              const float* __restrict__ ctr,
              const float* __restrict__ g1, const float* __restrict__ be1,
              const float* __restrict__ b2, const float* __restrict__ g2,
              const float* __restrict__ be2,
              const _Float16* __restrict__ w1p,
              const _Float16* __restrict__ w2p,
              float* __restrict__ out0,      // patch_feature [8192][256]
              float* __restrict__ out1) {    // neighbor idx as float [8192][32]
    const int q = blockIdx.x;
    const int b = q >> 10;
    const int t = threadIdx.x;
    const int w = t >> 6;
    const int lane = t & 63;
    const int quad = lane >> 4;
    const int l15  = lane & 15;

    // Overlaid region: Xs f16[32][104] (phase1 -> GEMM1) then H16 f16[32][264]
    // (C-store -> phase 6). Transition fenced by the barrier after GEMM1.
    __shared__ __align__(16) unsigned char H16raw[KN * HSTR * 2];  // 16896
    __shared__ __align__(16) _Float16 lnph[4 * 256];               // 2048: g1,be1,g2,be2
    __shared__ int nbr[KN];
    __shared__ int wcnt[2][4];

    _Float16 (*H16)[HSTR] = (_Float16(*)[HSTR])H16raw;
    _Float16 (*Xs)[104]   = (_Float16(*)[104])H16raw;   // OVERLAY
    _Float16* g1h  = lnph;
    _Float16* be1h = lnph + 256;
    _Float16* g2h  = lnph + 512;
    _Float16* be2h = lnph + 768;

    lnph[t]       = (_Float16)g1[t];
    lnph[256 + t] = (_Float16)be1[t];
    lnph[512 + t] = (_Float16)g2[t];
    lnph[768 + t] = (_Float16)be2[t];

    // ---- Phase 0: ball query (block-wide ordered compaction) ----
    // first-32-ascending == reference sort+slice; exact unfused fp32 formula.
    const float* xb = xyz + (size_t)b * NPTS * 3;
    const float cx = ctr[q * 3 + 0];
    const float cy = ctr[q * 3 + 1];
    const float cz = ctr[q * 3 + 2];
    const float sc = __fadd_rn(__fadd_rn(__fmul_rn(cx, cx), __fmul_rn(cy, cy)),
                               __fmul_rn(cz, cz));

    int found = 0;
    int par = 0;
    for (int base = 0; base < NPTS; base += 256) {
        const int n = base + t;
        const float px = xb[n * 3 + 0];
        const float py = xb[n * 3 + 1];
        const float pz = xb[n * 3 + 2];
        const float sp = __fadd_rn(__fadd_rn(__fmul_rn(px, px), __fmul_rn(py, py)),
                                   __fmul_rn(pz, pz));
        const float dt = __fadd_rn(__fadd_rn(__fmul_rn(cx, px), __fmul_rn(cy, py)),
                                   __fmul_rn(cz, pz));
        const float sqr = __fsub_rn(__fadd_rn(sc, sp), __fmul_rn(2.0f, dt));
        const bool inball = (sqr <= 0.0625f);

        const unsigned long long m = __ballot(inball);
        if (lane == 0) wcnt[par][w] = (int)__popcll(m);
        __syncthreads();
        int pre = found;
        if (w > 0) pre += wcnt[par][0];
        if (w > 1) pre += wcnt[par][1];
        if (w > 2) pre += wcnt[par][2];
        const int tot = found + wcnt[par][0] + wcnt[par][1] + wcnt[par][2] + wcnt[par][3];
        const int pos = pre + (int)__popcll(m & ((1ull << lane) - 1ull));
        if (inball && pos < KN) nbr[pos] = n;
        found = tot;                  // block-uniform
        par ^= 1;
        if (found >= KN) break;
    }
    __syncthreads();                  // nbr visible to all
    const int count = (found < KN) ? found : KN;
    const int first = (count > 0) ? nbr[0] : NPTS;

    if (t < KN)
        out1[(size_t)q * KN + t] = (float)((t < count) ? nbr[t] : first);

    // ---- Phase 1: gather + rel + posenc into Xs (f16; k=91 is 1.0 for b1) ----
    {
        const int k  = t >> 3;
        const int tc = t & 7;
        const int nidx = (k < count) ? nbr[k] : first;
        const int n = (nidx < NPTS) ? nidx : NPTS - 1;   // JAX OOB gather clamp
        const float rx = xb[n * 3 + 0] - cx;
        const float ry = xb[n * 3 + 1] - cy;
        const float rz = xb[n * 3 + 2] - cz;
        const float* pfr = pf + ((size_t)b * NPTS + n) * 64;

        const float4 f0 = *(const float4*)(pfr + tc * 8);
        const float4 f1 = *(const float4*)(pfr + tc * 8 + 4);
        half8 hv;
        hv[0] = (_Float16)f0.x; hv[1] = (_Float16)f0.y;
        hv[2] = (_Float16)f0.z; hv[3] = (_Float16)f0.w;
        hv[4] = (_Float16)f1.x; hv[5] = (_Float16)f1.y;
        hv[6] = (_Float16)f1.z; hv[7] = (_Float16)f1.w;
        *(half8*)&Xs[k][tc * 8] = hv;

        half4v ov;
        #pragma unroll
        for (int j = 0; j < 4; ++j) {
            const int c = 64 + tc * 4 + j;
            float v;
            if (c < 67) {
                v = (c == 64) ? rx : ((c == 65) ? ry : rz);
            } else if (c < 91) {
                const int jj = c - 67;
                const int d = jj >> 3;
                const int mm = jj & 7;
                const float f = (float)(1 << (mm & 3));
                const float r = (d == 0) ? rx : ((d == 1) ? ry : rz);
                v = (mm < 4) ? __sinf(r * f) : __cosf(r * f);
            } else if (c == 91) {
                v = 1.0f;               // bias row (b1 folded into W1 pack)
            } else {
                v = 0.0f;
            }
            ov[j] = (_Float16)v;
        }
        *(half4v*)&Xs[k][64 + tc * 4] = ov;
    }
    __syncthreads();

    f32x4 acc[2][4];   // lane: ch=(w*4+nt)*16+quad*4+r, pt=mt*16+l15

    // ---- GEMM1: W1^T as A, X as B  ->  acc (b1 via folded row) ----
    #pragma unroll
    for (int mt = 0; mt < 2; ++mt)
        #pragma unroll
        for (int nt = 0; nt < 4; ++nt)
            acc[mt][nt] = (f32x4){0.f, 0.f, 0.f, 0.f};

    #pragma unroll
    for (int kt = 0; kt < 3; ++kt) {
        const half8 x0 = *(const half8*)&Xs[l15][kt * 32 + quad * 8];
        const half8 x1 = *(const half8*)&Xs[16 + l15][kt * 32 + quad * 8];
        #pragma unroll
        for (int nt = 0; nt < 4; ++nt) {
            const half8 wf = *(const half8*)&w1p[((kt * 16 + w * 4 + nt) * 64 + lane) * 8];
            acc[0][nt] = __builtin_amdgcn_mfma_f32_16x16x32_f16(wf, x0, acc[0][nt], 0, 0, 0);
            acc[1][nt] = __builtin_amdgcn_mfma_f32_16x16x32_f16(wf, x1, acc[1][nt], 0, 0, 0);
        }
    }
    __syncthreads();   // overlay fence: all Xs reads done before H16 stores

    // ---- C-store GEMM1: raw f16, 8 contiguous ds_write_b64 (acc dies here) ----
    #pragma unroll
    for (int nt = 0; nt < 4; ++nt) {
        const int chb = (w * 4 + nt) * 16 + quad * 4;
        #pragma unroll
        for (int mt = 0; mt < 2; ++mt) {
            half4v h;
            #pragma unroll
            for (int r = 0; r < 4; ++r)
                h[r] = (_Float16)acc[mt][nt][r];
            *(half4v*)&H16[mt * 16 + l15][chb] = h;
        }
    }
    __syncthreads();

    const int row = t >> 3;         // LN ownership: thread = (row, octet p)
    const int p   = t & 7;          // owns cols [16p,16p+16) and [128+16p,+16)
    _Float16* hrow0 = &H16[row][16 * p];
    _Float16* hrow1 = &H16[row][128 + 16 * p];
    half2t ones;
    ones[0] = (_Float16)1.0f;
    ones[1] = (_Float16)1.0f;

    // ---- Phase 3: LN1 + GeLU, in place on H16 (round-8 scheme) ----
    {
        H8u u0, u1, u2, u3;
        u0.v = *(const half8*)hrow0;
        u1.v = *(const half8*)(hrow0 + 8);
        u2.v = *(const half8*)hrow1;
        u3.v = *(const half8*)(hrow1 + 8);

        float s = 0.0f, s2 = 0.0f;
        stat8(u0, ones, s, s2); stat8(u1, ones, s, s2);
        stat8(u2, ones, s, s2); stat8(u3, ones, s, s2);
        #pragma unroll
        for (int off = 1; off < 8; off <<= 1) {
            s  += __shfl_xor(s, off, 64);
            s2 += __shfl_xor(s2, off, 64);
        }
        const float mu  = s * (1.0f / 256.0f);
        const float var = fmaf(s2, 1.0f / 256.0f, -mu * mu);
        const float rs  = __builtin_amdgcn_rsqf(var + 1e-5f);
        half2t rsh, nmuh;
        rsh[0]  = (_Float16)rs;    rsh[1]  = (_Float16)rs;
        nmuh[0] = (_Float16)(-mu); nmuh[1] = (_Float16)(-mu);

        H8u gA0, gA1, gB0, gB1, bA0, bA1, bB0, bB1;
        gA0.v = *(const half8*)&g1h[16 * p];        bA0.v = *(const half8*)&be1h[16 * p];
        gA1.v = *(const half8*)&g1h[16 * p + 8];    bA1.v = *(const half8*)&be1h[16 * p + 8];
        gB0.v = *(const half8*)&g1h[128 + 16 * p];  bB0.v = *(const half8*)&be1h[128 + 16 * p];
        gB1.v = *(const half8*)&g1h[136 + 16 * p];  bB1.v = *(const half8*)&be1h[136 + 16 * p];

        norm_gelu8(u0, gA0, bA0, rsh, nmuh);
        norm_gelu8(u1, gA1, bA1, rsh, nmuh);
        norm_gelu8(u2, gB0, bB0, rsh, nmuh);
        norm_gelu8(u3, gB1, bB1, rsh, nmuh);

        *(half8*)hrow0       = u0.v;
        *(half8*)(hrow0 + 8) = u1.v;
        *(half8*)hrow1       = u2.v;
        *(half8*)(hrow1 + 8) = u3.v;
    }
    __syncthreads();

    // ---- GEMM2: W2^T as A, H as B ----
    #pragma unroll
    for (int mt = 0; mt < 2; ++mt)
        #pragma unroll
        for (int nt = 0; nt < 4; ++nt)
            acc[mt][nt] = (f32x4){0.f, 0.f, 0.f, 0.f};

    #pragma unroll
    for (int kt = 0; kt < 8; ++kt) {
        const half8 h0 = *(const half8*)&H16[l15][kt * 32 + quad * 8];
        const half8 h1 = *(const half8*)&H16[16 + l15][kt * 32 + quad * 8];
        #pragma unroll
        for (int nt = 0; nt < 4; ++nt) {
            const half8 wf = *(const half8*)&w2p[((kt * 16 + w * 4 + nt) * 64 + lane) * 8];
            acc[0][nt] = __builtin_amdgcn_mfma_f32_16x16x32_f16(wf, h0, acc[0][nt], 0, 0, 0);
            acc[1][nt] = __builtin_amdgcn_mfma_f32_16x16x32_f16(wf, h1, acc[1][nt], 0, 0, 0);
        }
    }
    __syncthreads();   // ALL B-reads of H16 done before in-place C-store

    // ---- C-store GEMM2: +b2, raw f16, contiguous b64 (acc dies here) ----
    #pragma unroll
    for (int nt = 0; nt < 4; ++nt) {
        const int chb = (w * 4 + nt) * 16 + quad * 4;
        const f32x4 bv = *(const f32x4*)&b2[chb];
        #pragma unroll
        for (int mt = 0; mt < 2; ++mt) {
            half4v h;
            #pragma unroll
            for (int r = 0; r < 4; ++r)
                h[r] = (_Float16)(acc[mt][nt][r] + bv[r]);
            *(half4v*)&H16[mt * 16 + l15][chb] = h;
        }
    }
    __syncthreads();

    // ---- Phase 5: LN2 (no activation), in place on H16 ----
    {
        H8u u0, u1, u2, u3;
        u0.v = *(const half8*)hrow0;
        u1.v = *(const half8*)(hrow0 + 8);
        u2.v = *(const half8*)hrow1;
        u3.v = *(const half8*)(hrow1 + 8);

        float s = 0.0f, s2 = 0.0f;
        stat8(u0, ones, s, s2); stat8(u1, ones, s, s2);
        stat8(u2, ones, s, s2); stat8(u3, ones, s, s2);
        #pragma unroll
        for (int off = 1; off < 8; off <<= 1) {
            s  += __shfl_xor(s, off, 64);
            s2 += __shfl_xor(s2, off, 64);
        }
        const float mu  = s * (1.0f / 256.0f);
        const float var = fmaf(s2, 1.0f / 256.0f, -mu * mu);
        const float rs  = __builtin_amdgcn_rsqf(var + 1e-5f);
        half2t rsh, nmuh;
        rsh[0]  = (_Float16)rs;    rsh[1]  = (_Float16)rs;
        nmuh[0] = (_Float16)(-mu); nmuh[1] = (_Float16)(-mu);

        H8u gA0, gA1, gB0, gB1, bA0, bA1, bB0, bB1;
        gA0.v = *(const half8*)&g2h[16 * p];        bA0.v = *(const half8*)&be2h[16 * p];
        gA1.v = *(const half8*)&g2h[16 * p + 8];    bA1.v = *(const half8*)&be2h[16 * p + 8];
        gB0.v = *(const half8*)&g2h[128 + 16 * p];  bB0.v = *(const half8*)&be2h[128 + 16 * p];
        gB1.v = *(const half8*)&g2h[136 + 16 * p];  bB1.v = *(const half8*)&be2h[136 + 16 * p];

        norm8(u0, gA0, bA0, rsh, nmuh);
        norm8(u1, gA1, bA1, rsh, nmuh);
        norm8(u2, gB0, bB0, rsh, nmuh);
        norm8(u3, gB1, bB1, rsh, nmuh);

        *(half8*)hrow0       = u0.v;
        *(half8*)(hrow0 + 8) = u1.v;
        *(half8*)hrow1       = u2.v;
        *(half8*)(hrow1 + 8) = u3.v;
    }
    __syncthreads();

    // ---- Phase 6: packed max over 32 points, coalesced float2 store ----
    if (t < 128) {
        const _Float16* Hf = &H16[0][0];
        half2t mx = *(const half2t*)(Hf + 2 * t);
        #pragma unroll
        for (int r = 1; r < KN; ++r) {
            const half2t v = *(const half2t*)(Hf + r * HSTR + 2 * t);
            mx = __builtin_elementwise_max(mx, v);
        }
        float2 o2;
        o2.x = (float)mx[0];
        o2.y = (float)mx[1];
        *(float2*)&out0[(size_t)q * C + 2 * t] = o2;
    }
}

extern "C" void kernel_launch(void* const* d_in, const int* in_sizes, int n_in,
                              void* d_out, int out_size, void* d_ws, size_t ws_size,
                              hipStream_t stream) {
    const float* xyz = (const float*)d_in[0];
    const float* pf  = (const float*)d_in[1];
    const float* ctr = (const float*)d_in[2];
    const float* W1  = (const float*)d_in[3];
    const float* b1  = (const float*)d_in[4];
    const float* g1  = (const float*)d_in[5];
    const float* be1 = (const float*)d_in[6];
    const float* W2  = (const float*)d_in[7];
    const float* b2  = (const float*)d_in[8];
    const float* g2  = (const float*)d_in[9];
    const float* be2 = (const float*)d_in[10];

    float* out = (float*)d_out;
    _Float16* wp = (_Float16*)d_ws;

    prep_w_kernel<<<(96 * 256 + 65536) / 256, 256, 0, stream>>>(W1, b1, W2, wp);
    encoder_fused<<<NQ, 256, 0, stream>>>(xyz, pf, ctr,
                                          g1, be1, b2, g2, be2,
                                          wp, wp + W1P_ELEMS,
                                          out, out + PF_ELEMS);
}

// Round 13
// 190.318 us; speedup vs baseline: 1.0372x; 1.0127x over previous
//
#include <hip/hip_runtime.h>
#include <math.h>

#define NPTS 16384
#define KN 32
#define C 256
#define NQ 8192              // 8 * 1024 queries
#define PF_ELEMS (NQ * C)

#define W1P_ELEMS (3 * 16 * 64 * 8)                 // 24576  (Ktiles=3, Ntiles=16)
#define W2P_ELEMS (8 * 16 * 64 * 8)                 // 65536  (Ktiles=8)
#define HSTR 264                                    // halves per H16 row

typedef _Float16 half8 __attribute__((ext_vector_type(8)));
typedef _Float16 half4v __attribute__((ext_vector_type(4)));
typedef _Float16 half2t __attribute__((ext_vector_type(2)));
typedef float f32x4 __attribute__((ext_vector_type(4)));

union H8u { half8 v; half2t h2[4]; };

__device__ __forceinline__ float fdot2f(half2t a, half2t b, float c) {
#if __has_builtin(__builtin_amdgcn_fdot2)
    return __builtin_amdgcn_fdot2(a, b, c, false);
#else
    return fmaf((float)a[1], (float)b[1], fmaf((float)a[0], (float)b[0], c));
#endif
}

// tanh-approx GeLU: max err ~3e-4.  y = x - x/(e^{2u}+1)
__device__ __forceinline__ float gelu_tanh(float x) {
    const float t  = x * x;
    const float p2 = fmaf(t, 0.0713548162726f, 1.59576912161f);
    const float e  = __expf(x * p2);
    return x - x * __builtin_amdgcn_rcpf(e + 1.0f);
}

__device__ __forceinline__ void stat8(const H8u& u, half2t ones, float& s, float& s2) {
    #pragma unroll
    for (int j = 0; j < 4; ++j) {
        s  = fdot2f(u.h2[j], ones, s);
        s2 = fdot2f(u.h2[j], u.h2[j], s2);
    }
}

__device__ __forceinline__ void norm_gelu8(H8u& u, const H8u& g, const H8u& be,
                                           half2t rsh, half2t nmuh) {
    #pragma unroll
    for (int j = 0; j < 4; ++j) {
        const half2t A = g.h2[j] * rsh;
        const half2t B = A * nmuh + be.h2[j];
        const half2t y = u.h2[j] * A + B;
        half2t o;
        o[0] = (_Float16)gelu_tanh((float)y[0]);
        o[1] = (_Float16)gelu_tanh((float)y[1]);
        u.h2[j] = o;
    }
}

__device__ __forceinline__ void norm8(H8u& u, const H8u& g, const H8u& be,
                                      half2t rsh, half2t nmuh) {
    #pragma unroll
    for (int j = 0; j < 4; ++j) {
        const half2t A = g.h2[j] * rsh;
        const half2t B = A * nmuh + be.h2[j];
        u.h2[j] = u.h2[j] * A + B;
    }
}

// ---------------------------------------------------------------------------
// Pack W1 (91x256 + b1 folded at k=91, K-padded to 96) and W2 (256x256) into
// f16 fragment order (layout verified round 2):
//   flat = ((kt*16 + nt)*64 + lane)*8 + j
//   k = kt*32 + (lane>>4)*8 + j ;  ch = nt*16 + (lane&15)
// ---------------------------------------------------------------------------
__global__ void prep_w_kernel(const float* __restrict__ W1,
                              const float* __restrict__ b1,
                              const float* __restrict__ W2,
                              _Float16* __restrict__ wp) {
    const int idx = blockIdx.x * 256 + threadIdx.x;   // 0 .. 90111
    if (idx < 96 * 256) {
        const int k = idx >> 8, n = idx & 255;
        const float v = (k < 91) ? W1[k * 256 + n] : ((k == 91) ? b1[n] : 0.0f);
        const int kt = k >> 5, quad = (k >> 3) & 3, j = k & 7;
        const int nt = n >> 4, l15 = n & 15;
        wp[(((kt * 16 + nt) * 64) + quad * 16 + l15) * 8 + j] = (_Float16)v;
    } else {
        const int e = idx - 96 * 256;
        const int k = e >> 8, n = e & 255;
        const int kt = k >> 5, quad = (k >> 3) & 3, j = k & 7;
        const int nt = n >> 4, l15 = n & 15;
        wp[W1P_ELEMS + (((kt * 16 + nt) * 64) + quad * 16 + l15) * 8 + j] =
            (_Float16)W2[k * 256 + n];
    }
}

// ---------------------------------------------------------------------------
// Fused: ball-query + gather/posenc + MLP1(LN,GeLU) + MLP2(LN) + max.
// Round-13 = round-12 structure with __launch_bounds__(256,6):
// rounds 8/10/11/12 establish the register budget as binding — 7 waves/EU
// (73 regs) forces ~3.6 MB scratch (WRITE_SIZE 12.85 vs 9.2 MB); 6 waves/EU
// (85 regs) is spill-free. Swapped-operand MFMA (channels-in-lane C layout,
// 8 contiguous ds_write_b64 C-stores, b1 folded into W1 k=91), Xs/H16 LDS
// overlay (fence barrier after GEMM1), round-8 LDS-based LN epilogues.
// No runtime-indexed private arrays (round-3 lesson).
// ---------------------------------------------------------------------------
__global__ void __launch_bounds__(256, 6)
encoder_fused(const float* __restrict__ xyz,
              const float* __restrict__ pf,
              const float* __restrict__ ctr,
              const float* __restrict__ g1, const float* __restrict__ be1,
              const float* __restrict__ b2, const float* __restrict__ g2,
              const float* __restrict__ be2,
              const _Float16* __restrict__ w1p,
              const _Float16* __restrict__ w2p,
              float* __restrict__ out0,      // patch_feature [8192][256]
              float* __restrict__ out1) {    // neighbor idx as float [8192][32]
    const int q = blockIdx.x;
    const int b = q >> 10;
    const int t = threadIdx.x;
    const int w = t >> 6;
    const int lane = t & 63;
    const int quad = lane >> 4;
    const int l15  = lane & 15;

    // Overlaid region: Xs f16[32][104] (phase1 -> GEMM1) then H16 f16[32][264]
    // (C-store -> phase 6). Transition fenced by the barrier after GEMM1.
    __shared__ __align__(16) unsigned char H16raw[KN * HSTR * 2];  // 16896
    __shared__ __align__(16) _Float16 lnph[4 * 256];               // 2048: g1,be1,g2,be2
    __shared__ int nbr[KN];
    __shared__ int wcnt[2][4];

    _Float16 (*H16)[HSTR] = (_Float16(*)[HSTR])H16raw;
    _Float16 (*Xs)[104]   = (_Float16(*)[104])H16raw;   // OVERLAY
    _Float16* g1h  = lnph;
    _Float16* be1h = lnph + 256;
    _Float16* g2h  = lnph + 512;
    _Float16* be2h = lnph + 768;

    lnph[t]       = (_Float16)g1[t];
    lnph[256 + t] = (_Float16)be1[t];
    lnph[512 + t] = (_Float16)g2[t];
    lnph[768 + t] = (_Float16)be2[t];

    // ---- Phase 0: ball query (block-wide ordered compaction) ----
    // first-32-ascending == reference sort+slice; exact unfused fp32 formula.
    const float* xb = xyz + (size_t)b * NPTS * 3;
    const float cx = ctr[q * 3 + 0];
    const float cy = ctr[q * 3 + 1];
    const float cz = ctr[q * 3 + 2];
    const float sc = __fadd_rn(__fadd_rn(__fmul_rn(cx, cx), __fmul_rn(cy, cy)),
                               __fmul_rn(cz, cz));

    int found = 0;
    int par = 0;
    for (int base = 0; base < NPTS; base += 256) {
        const int n = base + t;
        const float px = xb[n * 3 + 0];
        const float py = xb[n * 3 + 1];
        const float pz = xb[n * 3 + 2];
        const float sp = __fadd_rn(__fadd_rn(__fmul_rn(px, px), __fmul_rn(py, py)),
                                   __fmul_rn(pz, pz));
        const float dt = __fadd_rn(__fadd_rn(__fmul_rn(cx, px), __fmul_rn(cy, py)),
                                   __fmul_rn(cz, pz));
        const float sqr = __fsub_rn(__fadd_rn(sc, sp), __fmul_rn(2.0f, dt));
        const bool inball = (sqr <= 0.0625f);

        const unsigned long long m = __ballot(inball);
        if (lane == 0) wcnt[par][w] = (int)__popcll(m);
        __syncthreads();
        int pre = found;
        if (w > 0) pre += wcnt[par][0];
        if (w > 1) pre += wcnt[par][1];
        if (w > 2) pre += wcnt[par][2];
        const int tot = found + wcnt[par][0] + wcnt[par][1] + wcnt[par][2] + wcnt[par][3];
        const int pos = pre + (int)__popcll(m & ((1ull << lane) - 1ull));
        if (inball && pos < KN) nbr[pos] = n;
        found = tot;                  // block-uniform
        par ^= 1;
        if (found >= KN) break;
    }
    __syncthreads();                  // nbr visible to all
    const int count = (found < KN) ? found : KN;
    const int first = (count > 0) ? nbr[0] : NPTS;

    if (t < KN)
        out1[(size_t)q * KN + t] = (float)((t < count) ? nbr[t] : first);

    // ---- Phase 1: gather + rel + posenc into Xs (f16; k=91 is 1.0 for b1) ----
    {
        const int k  = t >> 3;
        const int tc = t & 7;
        const int nidx = (k < count) ? nbr[k] : first;
        const int n = (nidx < NPTS) ? nidx : NPTS - 1;   // JAX OOB gather clamp
        const float rx = xb[n * 3 + 0] - cx;
        const float ry = xb[n * 3 + 1] - cy;
        const float rz = xb[n * 3 + 2] - cz;
        const float* pfr = pf + ((size_t)b * NPTS + n) * 64;

        const float4 f0 = *(const float4*)(pfr + tc * 8);
        const float4 f1 = *(const float4*)(pfr + tc * 8 + 4);
        half8 hv;
        hv[0] = (_Float16)f0.x; hv[1] = (_Float16)f0.y;
        hv[2] = (_Float16)f0.z; hv[3] = (_Float16)f0.w;
        hv[4] = (_Float16)f1.x; hv[5] = (_Float16)f1.y;
        hv[6] = (_Float16)f1.z; hv[7] = (_Float16)f1.w;
        *(half8*)&Xs[k][tc * 8] = hv;

        half4v ov;
        #pragma unroll
        for (int j = 0; j < 4; ++j) {
            const int c = 64 + tc * 4 + j;
            float v;
            if (c < 67) {
                v = (c == 64) ? rx : ((c == 65) ? ry : rz);
            } else if (c < 91) {
                const int jj = c - 67;
                const int d = jj >> 3;
                const int mm = jj & 7;
                const float f = (float)(1 << (mm & 3));
                const float r = (d == 0) ? rx : ((d == 1) ? ry : rz);
                v = (mm < 4) ? __sinf(r * f) : __cosf(r * f);
            } else if (c == 91) {
                v = 1.0f;               // bias row (b1 folded into W1 pack)
            } else {
                v = 0.0f;
            }
            ov[j] = (_Float16)v;
        }
        *(half4v*)&Xs[k][64 + tc * 4] = ov;
    }
    __syncthreads();

    f32x4 acc[2][4];   // lane: ch=(w*4+nt)*16+quad*4+r, pt=mt*16+l15

    // ---- GEMM1: W1^T as A, X as B  ->  acc (b1 via folded row) ----
    #pragma unroll
    for (int mt = 0; mt < 2; ++mt)
        #pragma unroll
        for (int nt = 0; nt < 4; ++nt)
            acc[mt][nt] = (f32x4){0.f, 0.f, 0.f, 0.f};

    #pragma unroll
    for (int kt = 0; kt < 3; ++kt) {
        const half8 x0 = *(const half8*)&Xs[l15][kt * 32 + quad * 8];
        const half8 x1 = *(const half8*)&Xs[16 + l15][kt * 32 + quad * 8];
        #pragma unroll
        for (int nt = 0; nt < 4; ++nt) {
            const half8 wf = *(const half8*)&w1p[((kt * 16 + w * 4 + nt) * 64 + lane) * 8];
            acc[0][nt] = __builtin_amdgcn_mfma_f32_16x16x32_f16(wf, x0, acc[0][nt], 0, 0, 0);
            acc[1][nt] = __builtin_amdgcn_mfma_f32_16x16x32_f16(wf, x1, acc[1][nt], 0, 0, 0);
        }
    }
    __syncthreads();   // overlay fence: all Xs reads done before H16 stores

    // ---- C-store GEMM1: raw f16, 8 contiguous ds_write_b64 (acc dies here) ----
    #pragma unroll
    for (int nt = 0; nt < 4; ++nt) {
        const int chb = (w * 4 + nt) * 16 + quad * 4;
        #pragma unroll
        for (int mt = 0; mt < 2; ++mt) {
            half4v h;
            #pragma unroll
            for (int r = 0; r < 4; ++r)
                h[r] = (_Float16)acc[mt][nt][r];
            *(half4v*)&H16[mt * 16 + l15][chb] = h;
        }
    }
    __syncthreads();

    const int row = t >> 3;         // LN ownership: thread = (row, octet p)
    const int p   = t & 7;          // owns cols [16p,16p+16) and [128+16p,+16)
    _Float16* hrow0 = &H16[row][16 * p];
    _Float16* hrow1 = &H16[row][128 + 16 * p];
    half2t ones;
    ones[0] = (_Float16)1.0f;
    ones[1] = (_Float16)1.0f;

    // ---- Phase 3: LN1 + GeLU, in place on H16 (round-8 scheme) ----
    {
        H8u u0, u1, u2, u3;
        u0.v = *(const half8*)hrow0;
        u1.v = *(const half8*)(hrow0 + 8);
        u2.v = *(const half8*)hrow1;
        u3.v = *(const half8*)(hrow1 + 8);

        float s = 0.0f, s2 = 0.0f;
        stat8(u0, ones, s, s2); stat8(u1, ones, s, s2);
        stat8(u2, ones, s, s2); stat8(u3, ones, s, s2);
        #pragma unroll
        for (int off = 1; off < 8; off <<= 1) {
            s  += __shfl_xor(s, off, 64);
            s2 += __shfl_xor(s2, off, 64);
        }
        const float mu  = s * (1.0f / 256.0f);
        const float var = fmaf(s2, 1.0f / 256.0f, -mu * mu);
        const float rs  = __builtin_amdgcn_rsqf(var + 1e-5f);
        half2t rsh, nmuh;
        rsh[0]  = (_Float16)rs;    rsh[1]  = (_Float16)rs;
        nmuh[0] = (_Float16)(-mu); nmuh[1] = (_Float16)(-mu);

        H8u gA0, gA1, gB0, gB1, bA0, bA1, bB0, bB1;
        gA0.v = *(const half8*)&g1h[16 * p];        bA0.v = *(const half8*)&be1h[16 * p];
        gA1.v = *(const half8*)&g1h[16 * p + 8];    bA1.v = *(const half8*)&be1h[16 * p + 8];
        gB0.v = *(const half8*)&g1h[128 + 16 * p];  bB0.v = *(const half8*)&be1h[128 + 16 * p];
        gB1.v = *(const half8*)&g1h[136 + 16 * p];  bB1.v = *(const half8*)&be1h[136 + 16 * p];

        norm_gelu8(u0, gA0, bA0, rsh, nmuh);
        norm_gelu8(u1, gA1, bA1, rsh, nmuh);
        norm_gelu8(u2, gB0, bB0, rsh, nmuh);
        norm_gelu8(u3, gB1, bB1, rsh, nmuh);

        *(half8*)hrow0       = u0.v;
        *(half8*)(hrow0 + 8) = u1.v;
        *(half8*)hrow1       = u2.v;
        *(half8*)(hrow1 + 8) = u3.v;
    }
    __syncthreads();

    // ---- GEMM2: W2^T as A, H as B ----
    #pragma unroll
    for (int mt = 0; mt < 2; ++mt)
        #pragma unroll
        for (int nt = 0; nt < 4; ++nt)
            acc[mt][nt] = (f32x4){0.f, 0.f, 0.f, 0.f};

    #pragma unroll
    for (int kt = 0; kt < 8; ++kt) {
        const half8 h0 = *(const half8*)&H16[l15][kt * 32 + quad * 8];
        const half8 h1 = *(const half8*)&H16[16 + l15][kt * 32 + quad * 8];
        #pragma unroll
        for (int nt = 0; nt < 4; ++nt) {
            const half8 wf = *(const half8*)&w2p[((kt * 16 + w * 4 + nt) * 64 + lane) * 8];
            acc[0][nt] = __builtin_amdgcn_mfma_f32_16x16x32_f16(wf, h0, acc[0][nt], 0, 0, 0);
            acc[1][nt] = __builtin_amdgcn_mfma_f32_16x16x32_f16(wf, h1, acc[1][nt], 0, 0, 0);
        }
    }
    __syncthreads();   // ALL B-reads of H16 done before in-place C-store

    // ---- C-store GEMM2: +b2, raw f16, contiguous b64 (acc dies here) ----
    #pragma unroll
    for (int nt = 0; nt < 4; ++nt) {
        const int chb = (w * 4 + nt) * 16 + quad * 4;
        const f32x4 bv = *(const f32x4*)&b2[chb];
        #pragma unroll
        for (int mt = 0; mt < 2; ++mt) {
            half4v h;
            #pragma unroll
            for (int r = 0; r < 4; ++r)
                h[r] = (_Float16)(acc[mt][nt][r] + bv[r]);
            *(half4v*)&H16[mt * 16 + l15][chb] = h;
        }
    }
    __syncthreads();

    // ---- Phase 5: LN2 (no activation), in place on H16 ----
    {
        H8u u0, u1, u2, u3;
        u0.v = *(const half8*)hrow0;
        u1.v = *(const half8*)(hrow0 + 8);
        u2.v = *(const half8*)hrow1;
        u3.v = *(const half8*)(hrow1 + 8);

        float s = 0.0f, s2 = 0.0f;
        stat8(u0, ones, s, s2); stat8(u1, ones, s, s2);
        stat8(u2, ones, s, s2); stat8(u3, ones, s, s2);
        #pragma unroll
        for (int off = 1; off < 8; off <<= 1) {
            s  += __shfl_xor(s, off, 64);
            s2 += __shfl_xor(s2, off, 64);
        }
        const float mu  = s * (1.0f / 256.0f);
        const float var = fmaf(s2, 1.0f / 256.0f, -mu * mu);
        const float rs  = __builtin_amdgcn_rsqf(var + 1e-5f);
        half2t rsh, nmuh;
        rsh[0]  = (_Float16)rs;    rsh[1]  = (_Float16)rs;
        nmuh[0] = (_Float16)(-mu); nmuh[1] = (_Float16)(-mu);

        H8u gA0, gA1, gB0, gB1, bA0, bA1, bB0, bB1;
        gA0.v = *(const half8*)&g2h[16 * p];        bA0.v = *(const half8*)&be2h[16 * p];
        gA1.v = *(const half8*)&g2h[16 * p + 8];    bA1.v = *(const half8*)&be2h[16 * p + 8];
        gB0.v = *(const half8*)&g2h[128 + 16 * p];  bB0.v = *(const half8*)&be2h[128 + 16 * p];
        gB1.v = *(const half8*)&g2h[136 + 16 * p];  bB1.v = *(const half8*)&be2h[136 + 16 * p];

        norm8(u0, gA0, bA0, rsh, nmuh);
        norm8(u1, gA1, bA1, rsh, nmuh);
        norm8(u2, gB0, bB0, rsh, nmuh);
        norm8(u3, gB1, bB1, rsh, nmuh);

        *(half8*)hrow0       = u0.v;
        *(half8*)(hrow0 + 8) = u1.v;
        *(half8*)hrow1       = u2.v;
        *(half8*)(hrow1 + 8) = u3.v;
    }
    __syncthreads();

    // ---- Phase 6: packed max over 32 points, coalesced float2 store ----
    if (t < 128) {
        const _Float16* Hf = &H16[0][0];
        half2t mx = *(const half2t*)(Hf + 2 * t);
        #pragma unroll
        for (int r = 1; r < KN; ++r) {
            const half2t v = *(const half2t*)(Hf + r * HSTR + 2 * t);
            mx = __builtin_elementwise_max(mx, v);
        }
        float2 o2;
        o2.x = (float)mx[0];
        o2.y = (float)mx[1];
        *(float2*)&out0[(size_t)q * C + 2 * t] = o2;
    }
}

extern "C" void kernel_launch(void* const* d_in, const int* in_sizes, int n_in,
                              void* d_out, int out_size, void* d_ws, size_t ws_size,
                              hipStream_t stream) {
    const float* xyz = (const float*)d_in[0];
    const float* pf  = (const float*)d_in[1];
    const float* ctr = (const float*)d_in[2];
    const float* W1  = (const float*)d_in[3];
    const float* b1  = (const float*)d_in[4];
    const float* g1  = (const float*)d_in[5];
    const float* be1 = (const float*)d_in[6];
    const float* W2  = (const float*)d_in[7];
    const float* b2  = (const float*)d_in[8];
    const float* g2  = (const float*)d_in[9];
    const float* be2 = (const float*)d_in[10];

    float* out = (float*)d_out;
    _Float16* wp = (_Float16*)d_ws;

    prep_w_kernel<<<(96 * 256 + 65536) / 256, 256, 0, stream>>>(W1, b1, W2, wp);
    encoder_fused<<<NQ, 256, 0, stream>>>(xyz, pf, ctr,
                                          g1, be1, b2, g2, be2,
                                          wp, wp + W1P_ELEMS,
                                          out, out + PF_ELEMS);
}